// Round 9
// baseline (1064.661 us; speedup 1.0000x reference)
//
#include <hip/hip_runtime.h>
#include <cstdint>
#include <cstddef>

#define RPB    8      // batch rows per block (= waves per block)
#define TMAX   512
#define HPITCH 72     // h_s row pitch in fp16 (64 + 8 pad -> kills 128B-stride bank conflict)

typedef _Float16 f16x8 __attribute__((ext_vector_type(8)));
typedef float    f32x4 __attribute__((ext_vector_type(4)));

// sigmoid (m1=-1, pa=1, pb=0) or tanh (m1=-2, pa=2, pb=-1) via tanh(x)=2*sig(2x)-1.
// Overflow-safe: exp->inf => rcp->0 => pb endpoint; exp->0 => pa+pb endpoint.
__device__ __forceinline__ float act_gate(float s, float m1, float pa, float pb) {
    float e = __expf(s * m1);
    return fmaf(__builtin_amdgcn_rcpf(1.f + e), pa, pb);
}

// Block = 512 threads = 8 waves = 8 batch rows.
// Gate matrix per step: G[8 x 256] = H[8 x 64] @ Whh^T, computed as MFMA
// 16x16x32_f16 tiles (M=16 half-used). Gate columns are PERMUTED:
// col' = unit*4 + gate  (j = (col'&3)*64 + (col'>>2) in original W rows), so
// wave w covers col' in [32w, 32w+32) = units [8w,8w+8) x 4 gates, and the
// update phase reads {i,f,g,o} for (row,unit) as ONE contiguous float4.
// Weight B-fragments: 4 named f16x8 = 16 VGPRs per wave, loop-invariant and
// small enough that RA actually keeps them (the 128-VGPR array never survived,
// rounds 2-8). Weight HBM/L1 traffic per step ~ 0; round 8 paid 32KB/row-step
// through L1 (51.5 GB total = the measured 655us floor).
// C-fragment layout (HW-verified m89): col = lane&15, row = (lane>>4)*4+reg.
// A/B k-slot convention: k = kt*32 + (lane>>4)*8 + e on BOTH operands -> any
// HW k-permutation cancels (A and B use identical slot mappings).
__global__ __launch_bounds__(512, 2)
void lstm_mfma_kernel(const float* __restrict__ ctx_g,   // (B, T)
                      const float* __restrict__ Wih_e,   // (256,1)
                      const float* __restrict__ Whh_e,   // (256,64)
                      const float* __restrict__ bih_e,
                      const float* __restrict__ bhh_e,
                      const float* __restrict__ Wih_d,
                      const float* __restrict__ Whh_d,
                      const float* __restrict__ bih_d,
                      const float* __restrict__ bhh_d,
                      const float* __restrict__ Whead,   // (1,64)
                      const float* __restrict__ bhead,   // (1,)
                      float* __restrict__ out,           // (B, n_steps)
                      int T, int n_steps)
{
    __shared__ __align__(16) float    ctx_s[RPB][TMAX];
    __shared__ __align__(16) float    gates_s[RPB][256];   // activated, col'=unit*4+gate
    __shared__ __align__(16) _Float16 h_s[16][HPITCH];     // rows 8..15 stay zero
    __shared__ float z_s[RPB];

    const int tid  = threadIdx.x;
    const int lane = tid & 63;
    const int w    = tid >> 6;          // wave id == owned batch row (0..7)
    const int b0   = blockIdx.x * RPB;
    const int c16  = lane & 15;         // MFMA col-in-tile / A row
    const int g4   = lane >> 4;         // MFMA k-group / C row-group
    const int gate = lane & 3;          // gate type of this lane's C columns
    const int rbase = (g4 & 1) * 4;     // valid C rows for g4<2; harmless alias for g4>=2

    // stage context rows (prologue only)
    for (int i = tid; i < RPB * T; i += 512) {
        int r = i / T, t = i - r * T;
        ctx_s[r][t] = ctx_g[(size_t)(b0 + r) * T + t];
    }
    // zero h (incl. pad and rows 8..15, which are never written again)
    for (int i = tid; i < 16 * HPITCH; i += 512)
        reinterpret_cast<_Float16*>(h_s)[i] = (_Float16)0;

    // activation constants: gate 2 (= g) is tanh, others sigmoid
    const float m1 = (gate == 2) ? -2.f : -1.f;
    const float pa = (gate == 2) ?  2.f :  1.f;
    const float pb = (gate == 2) ? -1.f :  0.f;

    // per-wave loop-invariant constants (re-filled for decoder)
    f16x8 b00, b01, b10, b11;           // B-frags [nt][kt], 16 VGPRs total
    float wih0, wih1, bias0, bias1;

    auto load_consts = [&](const float* Whh, const float* Wih,
                           const float* bih, const float* bhh) {
        const int cp0 = 32 * w + c16;
        const int cp1 = cp0 + 16;
        const int j0  = ((cp0 & 3) << 6) | (cp0 >> 2);
        const int j1  = ((cp1 & 3) << 6) | (cp1 >> 2);
        wih0 = Wih[j0];  bias0 = bih[j0] + bhh[j0];
        wih1 = Wih[j1];  bias1 = bih[j1] + bhh[j1];
        const float* p;
        f16x8 bb;
        #pragma unroll 1
        for (int q = 0; q < 4; ++q) {
            const int j  = (q >> 1) ? j1 : j0;
            const int kt = q & 1;
            p = Whh + j * 64 + kt * 32 + g4 * 8;
            #pragma unroll
            for (int e = 0; e < 8; ++e) bb[e] = (_Float16)p[e];
            if (q == 0) b00 = bb; else if (q == 1) b01 = bb;
            else if (q == 2) b10 = bb; else b11 = bb;
        }
    };

    load_consts(Whh_e, Wih_e, bih_e, bhh_e);
    const float wh = Whead[lane];
    const float bh = bhead[0];

    float c = 0.f;
    __syncthreads();

    // One LSTM step. x0..x3 = input x for this lane's C rows rbase+0..3.
    // Caller must __syncthreads() after (once per step, plus the one inside).
    auto do_step = [&](float x0, float x1, float x2, float x3) -> float {
        // A fragments from h (reads BEFORE the inner barrier)
        f16x8 a0 = *reinterpret_cast<const f16x8*>(&h_s[c16][g4 * 8]);
        f16x8 a1 = *reinterpret_cast<const f16x8*>(&h_s[c16][32 + g4 * 8]);
        f32x4 acc0, acc1;
        acc0[0] = fmaf(x0, wih0, bias0); acc0[1] = fmaf(x1, wih0, bias0);
        acc0[2] = fmaf(x2, wih0, bias0); acc0[3] = fmaf(x3, wih0, bias0);
        acc1[0] = fmaf(x0, wih1, bias1); acc1[1] = fmaf(x1, wih1, bias1);
        acc1[2] = fmaf(x2, wih1, bias1); acc1[3] = fmaf(x3, wih1, bias1);
        acc0 = __builtin_amdgcn_mfma_f32_16x16x32_f16(a0, b00, acc0, 0, 0, 0);
        acc0 = __builtin_amdgcn_mfma_f32_16x16x32_f16(a1, b01, acc0, 0, 0, 0);
        acc1 = __builtin_amdgcn_mfma_f32_16x16x32_f16(a0, b10, acc1, 0, 0, 0);
        acc1 = __builtin_amdgcn_mfma_f32_16x16x32_f16(a1, b11, acc1, 0, 0, 0);
        if (g4 < 2) {                        // C rows 0..7 are real
            const int col0 = 32 * w + c16;
            #pragma unroll
            for (int reg = 0; reg < 4; ++reg) {
                gates_s[rbase + reg][col0]      = act_gate(acc0[reg], m1, pa, pb);
                gates_s[rbase + reg][col0 + 16] = act_gate(acc1[reg], m1, pa, pb);
            }
        }
        __syncthreads();                     // gates visible; h reads done
        // update phase: lane owns (row=w, unit=lane)
        float4 gv = *reinterpret_cast<const float4*>(&gates_s[w][lane * 4]);
        c = fmaf(gv.y, c, gv.x * gv.z);      // c = f*c + i*g
        float e2 = __expf(-2.f * c);
        float th = fmaf(__builtin_amdgcn_rcpf(1.f + e2), 2.f, -1.f);
        float h  = gv.w * th;                // h = o * tanh(c)
        h_s[w][lane] = (_Float16)h;          // write AFTER inner barrier
        return h;
    };

    // ---------------- encoder: T sequential steps ----------------
    for (int t = 0; t < T; ++t) {
        float x0 = ctx_s[rbase + 0][t];
        float x1 = ctx_s[rbase + 1][t];
        float x2 = ctx_s[rbase + 2][t];
        float x3 = ctx_s[rbase + 3][t];
        do_step(x0, x1, x2, x3);
        __syncthreads();
    }

    // ---------------- decoder setup ----------------
    if (tid < RPB) z_s[tid] = ctx_s[tid][T - 1];   // z0 = context[:, -1]
    load_consts(Whh_d, Wih_d, bih_d, bhh_d);
    __syncthreads();

    // ---------------- decoder: n_steps sequential steps ----------------
    for (int s = 0; s < n_steps; ++s) {
        float x0 = z_s[rbase + 0];
        float x1 = z_s[rbase + 1];
        float x2 = z_s[rbase + 2];
        float x3 = z_s[rbase + 3];
        float h = do_step(x0, x1, x2, x3);
        // head: z[w] = sum_u h[w][u] * Whead[u] + bh  (in-wave butterfly)
        float p = h * wh;
        #pragma unroll
        for (int off = 32; off >= 1; off >>= 1)
            p += __shfl_xor(p, off);
        if (lane == 0) {
            const float zn = p + bh;
            z_s[w] = zn;
            out[(size_t)(b0 + w) * n_steps + s] = zn;
        }
        __syncthreads();
    }
}

extern "C" void kernel_launch(void* const* d_in, const int* in_sizes, int n_in,
                              void* d_out, int out_size, void* d_ws, size_t ws_size,
                              hipStream_t stream)
{
    const float* ctx   = (const float*)d_in[0];
    const float* Wih_e = (const float*)d_in[1];
    const float* Whh_e = (const float*)d_in[2];
    const float* bih_e = (const float*)d_in[3];
    const float* bhh_e = (const float*)d_in[4];
    const float* Wih_d = (const float*)d_in[5];
    const float* Whh_d = (const float*)d_in[6];
    const float* bih_d = (const float*)d_in[7];
    const float* bhh_d = (const float*)d_in[8];
    const float* Whead = (const float*)d_in[9];
    const float* bhead = (const float*)d_in[10];
    float* out = (float*)d_out;

    const int B = 2048;                 // fixed by the harness setup
    const int T = in_sizes[0] / B;      // 512
    const int n_steps = out_size / B;   // 256

    lstm_mfma_kernel<<<dim3(B / RPB), dim3(512), 0, stream>>>(
        ctx, Wih_e, Whh_e, bih_e, bhh_e,
        Wih_d, Whh_d, bih_d, bhh_d,
        Whead, bhead, out, T, n_steps);
}

// Round 10
// 652.277 us; speedup vs baseline: 1.6322x; 1.6322x over previous
//
#include <hip/hip_runtime.h>
#include <cstdint>
#include <cstddef>

#define ROWS   4      // batch rows per block
#define TMAX   512
#define HPITCH 72     // fp16 elems per h row (144B, 16B-aligned)
#define GPITCH 260    // fp32 per gates row (1040B, 16B-aligned)

typedef _Float16 f16x8 __attribute__((ext_vector_type(8)));
typedef float    f32x4 __attribute__((ext_vector_type(4)));

// sigmoid (m1=-1,pa=1,pb=0) / tanh (m1=-2,pa=2,pb=-1); overflow-safe.
__device__ __forceinline__ float act_gate(float s, float m1, float pa, float pb) {
    float e = __expf(s * m1);
    return fmaf(__builtin_amdgcn_rcpf(1.f + e), pa, pb);
}

// Block = 256 threads = 4 waves = 4 batch rows; grid = 512 blocks = 2/CU.
// Wave w owns permuted gate-cols [64w,64w+64) = units [16w,16w+16):
// col' = unit*4+gate, j = (col'&3)*64 + (col'>>2). Self-contained waves:
// the gate->update handoff is an intra-wave LDS round-trip (DS-pipe FIFO per
// wave, no barrier); ONE __syncthreads per step (for h). h_s and zpart are
// double-buffered so the single barrier is race-free. B-frags: 8 named f16x8
// = 32 VGPR/wave, loop-invariant (r9 proved this scale stays resident).
// MFMA mapping (numerically verified in r9): A=h rows c16, k=g4*8+e per
// 32-chunk; C col=lane&15(+16t), row=reg (M=4 used of 16).
__global__ __launch_bounds__(256, 2)
void lstm_mfma2_kernel(const float* __restrict__ ctx_g,
                       const float* __restrict__ Wih_e,
                       const float* __restrict__ Whh_e,
                       const float* __restrict__ bih_e,
                       const float* __restrict__ bhh_e,
                       const float* __restrict__ Wih_d,
                       const float* __restrict__ Whh_d,
                       const float* __restrict__ bih_d,
                       const float* __restrict__ bhh_d,
                       const float* __restrict__ Whead,
                       const float* __restrict__ bhead,
                       float* __restrict__ out,
                       int T, int n_steps)
{
    __shared__ __align__(16) float    ctx_s[ROWS][TMAX];
    __shared__ __align__(16) float    gates_s[ROWS][GPITCH];
    __shared__ __align__(16) _Float16 h_s[2][16][HPITCH];   // double-buffered
    __shared__ __align__(16) f32x4    zpart_s[2][4];        // [buf][wave]

    const int tid  = threadIdx.x;
    const int lane = tid & 63;
    const int w    = tid >> 6;          // wave id 0..3
    const int b0   = blockIdx.x * ROWS;
    const int c16  = lane & 15;         // MFMA col-in-tile
    const int g4   = lane >> 4;         // MFMA k-group
    const int uu   = lane & 15;         // update: unit-local
    const int ur   = lane >> 4;         // update: row 0..3
    const int unit = (w << 4) + uu;

    for (int r = 0; r < ROWS; ++r)
        for (int t = tid; t < T; t += 256)
            ctx_s[r][t] = ctx_g[(size_t)(b0 + r) * T + t];
    for (int i = tid; i < 2 * 16 * HPITCH; i += 256)
        reinterpret_cast<_Float16*>(h_s)[i] = (_Float16)0;

    const int gate = c16 & 3;           // same gate for all 4 tiles of a lane
    const float m1 = (gate == 2) ? -2.f : -1.f;
    const float pa = (gate == 2) ?  2.f :  1.f;
    const float pb = (gate == 2) ? -1.f :  0.f;

    const int cp0 = (w << 6) + c16;     // this lane's 4 N-tile columns
    const int cp1 = cp0 + 16, cp2 = cp0 + 32, cp3 = cp0 + 48;
    const int j0 = ((cp0 & 3) << 6) | (cp0 >> 2);
    const int j1 = ((cp1 & 3) << 6) | (cp1 >> 2);
    const int j2 = ((cp2 & 3) << 6) | (cp2 >> 2);
    const int j3 = ((cp3 & 3) << 6) | (cp3 >> 2);

    f16x8 b0k0, b0k1, b1k0, b1k1, b2k0, b2k1, b3k0, b3k1;  // 32 VGPRs
    float wih0, wih1, wih2, wih3, bs0, bs1, bs2, bs3;

    auto load_wts = [&](const float* Whh, const float* Wih,
                        const float* bih, const float* bhh) {
        auto ldb = [&](int j, int kc) {
            const float* p = Whh + j * 64 + kc * 32 + (g4 << 3);
            f16x8 v;
            #pragma unroll
            for (int e = 0; e < 8; ++e) v[e] = (_Float16)p[e];
            return v;
        };
        b0k0 = ldb(j0, 0); b0k1 = ldb(j0, 1);
        b1k0 = ldb(j1, 0); b1k1 = ldb(j1, 1);
        b2k0 = ldb(j2, 0); b2k1 = ldb(j2, 1);
        b3k0 = ldb(j3, 0); b3k1 = ldb(j3, 1);
        wih0 = Wih[j0]; bs0 = bih[j0] + bhh[j0];
        wih1 = Wih[j1]; bs1 = bih[j1] + bhh[j1];
        wih2 = Wih[j2]; bs2 = bih[j2] + bhh[j2];
        wih3 = Wih[j3]; bs3 = bih[j3] + bhh[j3];
    };

    load_wts(Whh_e, Wih_e, bih_e, bhh_e);
    const float wh = Whead[unit];
    const float bh = bhead[0];
    float c = 0.f;
    __syncthreads();

    // One step: reads h_s[cur], writes h_s[cur^1]. Caller barriers after.
    auto do_step = [&](f32x4 xv, int cur, bool head, int pz) {
        f16x8 a0 = *reinterpret_cast<const f16x8*>(&h_s[cur][c16][g4 << 3]);
        f16x8 a1 = *reinterpret_cast<const f16x8*>(&h_s[cur][c16][32 + (g4 << 3)]);
        f32x4 ac0, ac1, ac2, ac3;
        #pragma unroll
        for (int r = 0; r < 4; ++r) {
            ac0[r] = fmaf(xv[r], wih0, bs0);
            ac1[r] = fmaf(xv[r], wih1, bs1);
            ac2[r] = fmaf(xv[r], wih2, bs2);
            ac3[r] = fmaf(xv[r], wih3, bs3);
        }
        ac0 = __builtin_amdgcn_mfma_f32_16x16x32_f16(a0, b0k0, ac0, 0, 0, 0);
        ac0 = __builtin_amdgcn_mfma_f32_16x16x32_f16(a1, b0k1, ac0, 0, 0, 0);
        ac1 = __builtin_amdgcn_mfma_f32_16x16x32_f16(a0, b1k0, ac1, 0, 0, 0);
        ac1 = __builtin_amdgcn_mfma_f32_16x16x32_f16(a1, b1k1, ac1, 0, 0, 0);
        ac2 = __builtin_amdgcn_mfma_f32_16x16x32_f16(a0, b2k0, ac2, 0, 0, 0);
        ac2 = __builtin_amdgcn_mfma_f32_16x16x32_f16(a1, b2k1, ac2, 0, 0, 0);
        ac3 = __builtin_amdgcn_mfma_f32_16x16x32_f16(a0, b3k0, ac3, 0, 0, 0);
        ac3 = __builtin_amdgcn_mfma_f32_16x16x32_f16(a1, b3k1, ac3, 0, 0, 0);
        if (g4 == 0) {                   // C rows 0..3 valid (M=4)
            #pragma unroll
            for (int r = 0; r < 4; ++r) {
                gates_s[r][cp0] = act_gate(ac0[r], m1, pa, pb);
                gates_s[r][cp1] = act_gate(ac1[r], m1, pa, pb);
                gates_s[r][cp2] = act_gate(ac2[r], m1, pa, pb);
                gates_s[r][cp3] = act_gate(ac3[r], m1, pa, pb);
            }
        }
        // intra-wave handoff (DS FIFO per wave; same array -> compiler keeps order)
        float4 gv = *reinterpret_cast<const float4*>(&gates_s[ur][unit << 2]);
        c = fmaf(gv.y, c, gv.x * gv.z);          // c = f*c + i*g
        float e2 = __expf(-2.f * c);
        float th = fmaf(__builtin_amdgcn_rcpf(1.f + e2), 2.f, -1.f);
        float h  = gv.w * th;                    // h = o * tanh(c)
        h_s[cur ^ 1][ur][unit] = (_Float16)h;
        if (head) {                              // z partial over this wave's units
            float p = h * wh;
            p += __shfl_xor(p, 8);
            p += __shfl_xor(p, 4);
            p += __shfl_xor(p, 2);
            p += __shfl_xor(p, 1);
            if (uu == 0) reinterpret_cast<float*>(&zpart_s[pz][w])[ur] = p;
        }
    };

    // ---------------- encoder ----------------
    int cur = 0;
    for (int t = 0; t < T; ++t) {
        f32x4 xv;
        #pragma unroll
        for (int r = 0; r < 4; ++r) xv[r] = ctx_s[r][t];
        do_step(xv, cur, false, 0);
        cur ^= 1;
        __syncthreads();
    }

    // ---------------- decoder ----------------
    load_wts(Whh_d, Wih_d, bih_d, bhh_d);
    f32x4 z4;
    #pragma unroll
    for (int r = 0; r < 4; ++r) z4[r] = ctx_s[r][T - 1];   // z0

    int pz = 0;
    for (int s = 0; s < n_steps; ++s) {
        if (s > 0 && tid < 4) {          // out[:, s-1] = z_s (head of step s-1)
            float v = z4[0];
            if (tid == 1) v = z4[1];
            if (tid == 2) v = z4[2];
            if (tid == 3) v = z4[3];
            out[(size_t)(b0 + tid) * n_steps + (s - 1)] = v;
        }
        do_step(z4, cur, true, pz);
        cur ^= 1;
        __syncthreads();
        f32x4 zp = zpart_s[pz][0] + zpart_s[pz][1] + zpart_s[pz][2] + zpart_s[pz][3];
        #pragma unroll
        for (int r = 0; r < 4; ++r) z4[r] = zp[r] + bh;
        pz ^= 1;
    }
    if (tid < 4) {                       // final column
        float v = z4[0];
        if (tid == 1) v = z4[1];
        if (tid == 2) v = z4[2];
        if (tid == 3) v = z4[3];
        out[(size_t)(b0 + tid) * n_steps + (n_steps - 1)] = v;
    }
}

extern "C" void kernel_launch(void* const* d_in, const int* in_sizes, int n_in,
                              void* d_out, int out_size, void* d_ws, size_t ws_size,
                              hipStream_t stream)
{
    const float* ctx   = (const float*)d_in[0];
    const float* Wih_e = (const float*)d_in[1];
    const float* Whh_e = (const float*)d_in[2];
    const float* bih_e = (const float*)d_in[3];
    const float* bhh_e = (const float*)d_in[4];
    const float* Wih_d = (const float*)d_in[5];
    const float* Whh_d = (const float*)d_in[6];
    const float* bih_d = (const float*)d_in[7];
    const float* bhh_d = (const float*)d_in[8];
    const float* Whead = (const float*)d_in[9];
    const float* bhead = (const float*)d_in[10];
    float* out = (float*)d_out;

    const int B = 2048;                 // fixed by the harness setup
    const int T = in_sizes[0] / B;      // 512
    const int n_steps = out_size / B;   // 256

    lstm_mfma2_kernel<<<dim3(B / ROWS), dim3(256), 0, stream>>>(
        ctx, Wih_e, Whh_e, bih_e, bhh_e,
        Wih_d, Whh_d, bih_d, bhh_d,
        Whead, bhead, out, T, n_steps);
}